// Round 1
// baseline (617.232 us; speedup 1.0000x reference)
//
#include <hip/hip_runtime.h>
#include <hip/hip_bf16.h>

// Problem constants (WrappedLoRALinear)
#define B_N   4
#define S_N   2048
#define D_INN 4096
#define D_OUTN 4096
#define RANKN 16
#define AUX_DN 64
#define AUX_UN 64
#define M_N (B_N * S_N)   // 8192 rows

typedef __attribute__((ext_vector_type(8))) short  short8;   // 8 bf16 = 4 VGPRs (MFMA A/B frag)
typedef __attribute__((ext_vector_type(4))) float  floatx4;  // MFMA C/D frag

// f32 -> bf16 (round-to-nearest-even)
__device__ __forceinline__ unsigned short f2b(float f) {
    unsigned int u = __float_as_uint(f);
    u += 0x7FFFu + ((u >> 16) & 1u);
    return (unsigned short)(u >> 16);
}

// async global->LDS, 16B per lane; LDS dest = wave-uniform base + lane*16
__device__ __forceinline__ void gld16(const void* g, void* l) {
    __builtin_amdgcn_global_load_lds(
        (const __attribute__((address_space(1))) unsigned int*)g,
        (__attribute__((address_space(3))) unsigned int*)l,
        16, 0, 0);
}

// ---------------- f32 -> bf16 cast (8 elems / thread) ----------------
__global__ __launch_bounds__(256) void cast_bf16_kernel(
    const float* __restrict__ src, unsigned short* __restrict__ dst, int n8) {
    int i = blockIdx.x * 256 + threadIdx.x;
    if (i >= n8) return;
    const floatx4* s4 = (const floatx4*)src;
    floatx4 a = s4[2 * i], b = s4[2 * i + 1];
    short8 o;
    o[0] = (short)f2b(a[0]); o[1] = (short)f2b(a[1]);
    o[2] = (short)f2b(a[2]); o[3] = (short)f2b(a[3]);
    o[4] = (short)f2b(b[0]); o[5] = (short)f2b(b[1]);
    o[6] = (short)f2b(b[2]); o[7] = (short)f2b(b[3]);
    ((short8*)dst)[i] = o;
}

// ------------- down_bf16[b][r][i] = sum_a down_aux[i][a] * hyper_down[b][a][r] -------------
__global__ __launch_bounds__(256) void build_down_kernel(
    const float* __restrict__ down_aux,   // [D_IN][64]
    const float* __restrict__ hyper_down, // [B][64][16]
    unsigned short* __restrict__ down_b)  // [B][16][D_IN] bf16
{
    __shared__ float hd[AUX_DN * RANKN];  // 4 KB
    const int b = blockIdx.y;
    const int i = blockIdx.x * 256 + threadIdx.x;
    for (int t = threadIdx.x; t < AUX_DN * RANKN; t += 256)
        hd[t] = hyper_down[(size_t)b * AUX_DN * RANKN + t];
    __syncthreads();
    float acc[RANKN];
    #pragma unroll
    for (int r = 0; r < RANKN; ++r) acc[r] = 0.f;
    const float* da = down_aux + (size_t)i * AUX_DN;
    for (int a = 0; a < AUX_DN; ++a) {
        float v = da[a];
        #pragma unroll
        for (int r = 0; r < RANKN; ++r) acc[r] += v * hd[a * RANKN + r];
    }
    for (int r = 0; r < RANKN; ++r)
        down_b[((size_t)b * RANKN + r) * D_INN + i] = f2b(acc[r]);
}

// ------------- up_pad[b][o][0..15] = bf16(2 * sum_a up_aux[a][o] * hyper_up[b][r][a]); [16..31]=0 -------------
__global__ __launch_bounds__(256) void build_up_kernel(
    const float* __restrict__ up_aux,    // [64][D_OUT]
    const float* __restrict__ hyper_up,  // [B][16][64]
    unsigned short* __restrict__ up_pad) // [B][D_OUT][32] bf16
{
    __shared__ float hu[RANKN * AUX_UN];  // 4 KB
    const int b = blockIdx.y;
    const int o = blockIdx.x * 256 + threadIdx.x;
    for (int t = threadIdx.x; t < RANKN * AUX_UN; t += 256)
        hu[t] = hyper_up[(size_t)b * RANKN * AUX_UN + t];
    __syncthreads();
    float acc[RANKN];
    #pragma unroll
    for (int r = 0; r < RANKN; ++r) acc[r] = 0.f;
    for (int a = 0; a < AUX_UN; ++a) {
        float v = up_aux[(size_t)a * D_OUTN + o];
        #pragma unroll
        for (int r = 0; r < RANKN; ++r) acc[r] += v * hu[r * AUX_UN + a];
    }
    short8 o0, o1, z;
    #pragma unroll
    for (int r = 0; r < 8; ++r) {
        o0[r] = (short)f2b(2.f * acc[r]);
        o1[r] = (short)f2b(2.f * acc[8 + r]);
        z[r] = 0;
    }
    short8* dst = (short8*)(up_pad + ((size_t)b * D_OUTN + o) * 32);
    dst[0] = o0; dst[1] = o1; dst[2] = z; dst[3] = z;
}

// ------------- lr_pad[m][0..15] = bf16(low_rank[m][r]); [16..31]=0  (MFMA, direct from global) -------------
__global__ __launch_bounds__(256) void lowrank_kernel(
    const unsigned short* __restrict__ xb,  // [M][D_IN] bf16
    const unsigned short* __restrict__ dw,  // [B][16][D_IN] bf16
    unsigned short* __restrict__ lr)        // [M][32] bf16
{
    const int lane = threadIdx.x & 63, wave = threadIdx.x >> 6;
    const int r0 = blockIdx.x * 64 + wave * 16;     // 16 rows per wave
    const int batch = blockIdx.x >> 5;              // 32 blocks per batch
    const int fm = lane & 15, fq = lane >> 4;
    const unsigned short* pa = xb + (size_t)(r0 + fm) * D_INN + fq * 8;
    const unsigned short* pb = dw + ((size_t)batch * RANKN + fm) * D_INN + fq * 8;
    floatx4 acc = {0.f, 0.f, 0.f, 0.f};
    for (int k0 = 0; k0 < D_INN; k0 += 32) {
        short8 a = *(const short8*)(pa + k0);
        short8 b = *(const short8*)(pb + k0);
        acc = __builtin_amdgcn_mfma_f32_16x16x32_bf16(a, b, acc, 0, 0, 0);
    }
    #pragma unroll
    for (int r = 0; r < 4; ++r) {
        int grow = r0 + fq * 4 + r;                 // C layout: row = quad*4+reg, col = lane&15
        lr[(size_t)grow * 32 + fm] = f2b(acc[r]);
        lr[(size_t)grow * 32 + 16 + fm] = 0;
    }
}

// ------------- main GEMM: out = x @ W^T + bias + (lr_pad @ up_pad^T as the 129th K-step) -------------
// m97 structure: 128x128 tile, BK=32, 4 waves (2x2 of 64x64), global_load_lds width 16.
__global__ __launch_bounds__(256, 3) void gemm_kernel(
    const unsigned short* __restrict__ xb,   // [M][K] bf16
    const unsigned short* __restrict__ Wb,   // [N][K] bf16
    const unsigned short* __restrict__ lr,   // [M][32] bf16
    const unsigned short* __restrict__ up,   // [B][N][32] bf16 (x2 scale folded)
    const float* __restrict__ bias,          // [N]
    float* __restrict__ out)                 // [M][N]
{
    __shared__ __align__(16) unsigned short As[128 * 32];  // 8 KB
    __shared__ __align__(16) unsigned short Bs[128 * 32];  // 8 KB

    const int t = threadIdx.x;
    const int lane = t & 63, wave = t >> 6;
    const int m0 = blockIdx.y * 128, n0 = blockIdx.x * 128;
    const int batch = m0 >> 11;                 // 2048 rows / batch

    // staging: issue j covers rows j*64 + wave*16 + lane/4, cols (lane%4)*8..+8
    const int srow = wave * 16 + (lane >> 2);
    const int scol = (lane & 3) * 8;
    // fragment indices
    const int fm = lane & 15, fq = lane >> 4;
    const int wm = wave >> 1, wn = wave & 1;

    floatx4 acc[4][4];
    #pragma unroll
    for (int i = 0; i < 4; ++i)
        #pragma unroll
        for (int j = 0; j < 4; ++j)
            acc[i][j] = (floatx4){0.f, 0.f, 0.f, 0.f};

    unsigned short* sA0 = As + wave * 512;          // + lane*8 elems written by HW
    unsigned short* sA1 = As + 2048 + wave * 512;
    unsigned short* sB0 = Bs + wave * 512;
    unsigned short* sB1 = Bs + 2048 + wave * 512;

    const unsigned short* gA0 = xb + (size_t)(m0 + srow) * D_INN + scol;
    const unsigned short* gA1 = gA0 + (size_t)64 * D_INN;
    const unsigned short* gB0 = Wb + (size_t)(n0 + srow) * D_INN + scol;
    const unsigned short* gB1 = gB0 + (size_t)64 * D_INN;

    auto compute_step = [&]() {
        short8 af[4], bf[4];
        #pragma unroll
        for (int mi = 0; mi < 4; ++mi)
            af[mi] = *(const short8*)(As + (wm * 64 + mi * 16 + fm) * 32 + fq * 8);
        #pragma unroll
        for (int ni = 0; ni < 4; ++ni)
            bf[ni] = *(const short8*)(Bs + (wn * 64 + ni * 16 + fm) * 32 + fq * 8);
        #pragma unroll
        for (int mi = 0; mi < 4; ++mi)
            #pragma unroll
            for (int ni = 0; ni < 4; ++ni)
                acc[mi][ni] = __builtin_amdgcn_mfma_f32_16x16x32_bf16(
                    af[mi], bf[ni], acc[mi][ni], 0, 0, 0);
    };

    #pragma unroll 1
    for (int kt = 0; kt < D_INN / 32; ++kt) {
        gld16(gA0, sA0); gld16(gA1, sA1);
        gld16(gB0, sB0); gld16(gB1, sB1);
        gA0 += 32; gA1 += 32; gB0 += 32; gB1 += 32;
        __syncthreads();   // drains vmcnt(0): LDS tiles valid
        compute_step();
        __syncthreads();   // all waves done reading before overwrite
    }

    // 129th K-step: the rank-16 LoRA delta, padded to 32 (cols 16..31 are zero)
    {
        const unsigned short* tA0 = lr + (size_t)(m0 + srow) * 32 + scol;
        const unsigned short* tA1 = tA0 + 64 * 32;
        const unsigned short* tB0 = up + ((size_t)batch * D_OUTN + n0 + srow) * 32 + scol;
        const unsigned short* tB1 = tB0 + 64 * 32;
        gld16(tA0, sA0); gld16(tA1, sA1);
        gld16(tB0, sB0); gld16(tB1, sB1);
        __syncthreads();
        compute_step();
    }

    // epilogue: + bias, store f32. C layout: col = lane&15, row = quad*4 + reg
    #pragma unroll
    for (int ni = 0; ni < 4; ++ni) {
        const int col = n0 + wn * 64 + ni * 16 + fm;
        const float bv = bias[col];
        #pragma unroll
        for (int mi = 0; mi < 4; ++mi) {
            const int row = m0 + wm * 64 + mi * 16 + fq * 4;
            float* op = out + (size_t)row * D_OUTN + col;
            #pragma unroll
            for (int r = 0; r < 4; ++r)
                op[(size_t)r * D_OUTN] = acc[mi][ni][r] + bv;
        }
    }
}

extern "C" void kernel_launch(void* const* d_in, const int* in_sizes, int n_in,
                              void* d_out, int out_size, void* d_ws, size_t ws_size,
                              hipStream_t stream) {
    const float* x          = (const float*)d_in[0];  // [B,S,D_IN]
    const float* W          = (const float*)d_in[1];  // [D_OUT,D_IN]
    const float* bias       = (const float*)d_in[2];  // [D_OUT]
    const float* down_aux   = (const float*)d_in[3];  // [D_IN,64]
    const float* up_aux     = (const float*)d_in[4];  // [64,D_OUT]
    const float* hyper_down = (const float*)d_in[5];  // [B,64,16]
    const float* hyper_up   = (const float*)d_in[6];  // [B,16,64]
    float* out = (float*)d_out;
    (void)in_sizes; (void)n_in; (void)out_size; (void)ws_size;

    // workspace layout (bf16/ushort elements), total ~103 MB
    unsigned short* ws = (unsigned short*)d_ws;
    unsigned short* Wb = ws;                                   // [4096][4096]
    unsigned short* xb = Wb + (size_t)D_OUTN * D_INN;          // [8192][4096]
    unsigned short* lr = xb + (size_t)M_N * D_INN;             // [8192][32]
    unsigned short* up = lr + (size_t)M_N * 32;                // [4][4096][32]
    unsigned short* dw = up + (size_t)B_N * D_OUTN * 32;       // [4][16][4096]

    cast_bf16_kernel<<<(D_OUTN * D_INN / 8) / 256, 256, 0, stream>>>(W, Wb, D_OUTN * D_INN / 8);
    cast_bf16_kernel<<<((size_t)M_N * D_INN / 8) / 256, 256, 0, stream>>>(x, xb, M_N * D_INN / 8);
    build_down_kernel<<<dim3(D_INN / 256, B_N), 256, 0, stream>>>(down_aux, hyper_down, dw);
    build_up_kernel<<<dim3(D_OUTN / 256, B_N), 256, 0, stream>>>(up_aux, hyper_up, up);
    lowrank_kernel<<<M_N / 64, 256, 0, stream>>>(xb, dw, lr);
    gemm_kernel<<<dim3(D_OUTN / 128, M_N / 128), 256, 0, stream>>>(xb, Wb, lr, up, bias, out);
}

// Round 2
// 598.923 us; speedup vs baseline: 1.0306x; 1.0306x over previous
//
#include <hip/hip_runtime.h>
#include <hip/hip_bf16.h>

// Problem constants (WrappedLoRALinear)
#define B_N   4
#define S_N   2048
#define D_INN 4096
#define D_OUTN 4096
#define RANKN 16
#define AUX_DN 64
#define AUX_UN 64
#define M_N (B_N * S_N)   // 8192 rows
#define KSPLIT 8          // lowrank K-split factor (K-chunk = 512)

typedef __attribute__((ext_vector_type(8))) short  short8;   // 8 bf16 = 4 VGPRs (MFMA A/B frag)
typedef __attribute__((ext_vector_type(4))) float  floatx4;  // MFMA C/D frag

// f32 -> bf16 (round-to-nearest-even)
__device__ __forceinline__ unsigned short f2b(float f) {
    unsigned int u = __float_as_uint(f);
    u += 0x7FFFu + ((u >> 16) & 1u);
    return (unsigned short)(u >> 16);
}

// async global->LDS, 16B per lane; LDS dest = wave-uniform base + lane*16
__device__ __forceinline__ void gld16(const void* g, void* l) {
    __builtin_amdgcn_global_load_lds(
        (const __attribute__((address_space(1))) unsigned int*)g,
        (__attribute__((address_space(3))) unsigned int*)l,
        16, 0, 0);
}

// ---------------- fused f32 -> bf16 cast for W then x (8 elems / thread) ----------------
__global__ __launch_bounds__(256) void cast2_bf16_kernel(
    const float* __restrict__ srcA, unsigned short* __restrict__ dstA, int nA8,
    const float* __restrict__ srcB, unsigned short* __restrict__ dstB, int nB8) {
    int i = blockIdx.x * 256 + threadIdx.x;
    const float* src; unsigned short* dst; int j;
    if (i < nA8) { src = srcA; dst = dstA; j = i; }
    else         { j = i - nA8; if (j >= nB8) return; src = srcB; dst = dstB; }
    const floatx4* s4 = (const floatx4*)src;
    floatx4 a = s4[2 * j], b = s4[2 * j + 1];
    short8 o;
    o[0] = (short)f2b(a[0]); o[1] = (short)f2b(a[1]);
    o[2] = (short)f2b(a[2]); o[3] = (short)f2b(a[3]);
    o[4] = (short)f2b(b[0]); o[5] = (short)f2b(b[1]);
    o[6] = (short)f2b(b[2]); o[7] = (short)f2b(b[3]);
    ((short8*)dst)[j] = o;
}

// ------------- fused factor build: z=0 -> down_bf16, z=1 -> up_pad -------------
// down_b[b][r][i] = bf16( sum_a down_aux[i][a] * hyper_down[b][a][r] )
// up_pad[b][o][0..15] = bf16( 2 * sum_a up_aux[a][o] * hyper_up[b][r][a] ); [16..31]=0
__global__ __launch_bounds__(256) void build_factors_kernel(
    const float* __restrict__ down_aux,   // [D_IN][64]
    const float* __restrict__ hyper_down, // [B][64][16]
    const float* __restrict__ up_aux,     // [64][D_OUT]
    const float* __restrict__ hyper_up,   // [B][16][64]
    unsigned short* __restrict__ down_b,  // [B][16][D_IN] bf16
    unsigned short* __restrict__ up_pad)  // [B][D_OUT][32] bf16
{
    __shared__ float h[AUX_DN * RANKN];  // 4 KB
    const int b = blockIdx.y;
    const int i = blockIdx.x * 256 + threadIdx.x;
    if (blockIdx.z == 0) {
        for (int t = threadIdx.x; t < AUX_DN * RANKN; t += 256)
            h[t] = hyper_down[(size_t)b * AUX_DN * RANKN + t];
        __syncthreads();
        float acc[RANKN];
        #pragma unroll
        for (int r = 0; r < RANKN; ++r) acc[r] = 0.f;
        const floatx4* da4 = (const floatx4*)(down_aux + (size_t)i * AUX_DN);
        #pragma unroll
        for (int a4 = 0; a4 < AUX_DN / 4; ++a4) {
            floatx4 v = da4[a4];
            #pragma unroll
            for (int jj = 0; jj < 4; ++jj) {
                float vv = v[jj];
                #pragma unroll
                for (int r = 0; r < RANKN; ++r) acc[r] += vv * h[(a4 * 4 + jj) * RANKN + r];
            }
        }
        #pragma unroll
        for (int r = 0; r < RANKN; ++r)
            down_b[((size_t)b * RANKN + r) * D_INN + i] = f2b(acc[r]);
    } else {
        for (int t = threadIdx.x; t < RANKN * AUX_UN; t += 256)
            h[t] = hyper_up[(size_t)b * RANKN * AUX_UN + t];
        __syncthreads();
        float acc[RANKN];
        #pragma unroll
        for (int r = 0; r < RANKN; ++r) acc[r] = 0.f;
        for (int a = 0; a < AUX_UN; ++a) {
            float v = up_aux[(size_t)a * D_OUTN + i];
            #pragma unroll
            for (int r = 0; r < RANKN; ++r) acc[r] += v * h[r * AUX_UN + a];
        }
        short8 o0, o1, z;
        #pragma unroll
        for (int r = 0; r < 8; ++r) {
            o0[r] = (short)f2b(2.f * acc[r]);
            o1[r] = (short)f2b(2.f * acc[8 + r]);
            z[r] = 0;
        }
        short8* dst = (short8*)(up_pad + ((size_t)b * D_OUTN + i) * 32);
        dst[0] = o0; dst[1] = o1; dst[2] = z; dst[3] = z;
    }
}

// ------------- low_rank partials, K-split: part[ks][m][r] (f32) -------------
__global__ __launch_bounds__(256) void lowrank_split_kernel(
    const unsigned short* __restrict__ xb,  // [M][D_IN] bf16
    const unsigned short* __restrict__ dw,  // [B][16][D_IN] bf16
    float* __restrict__ part)               // [KSPLIT][M][16] f32
{
    const int lane = threadIdx.x & 63, wave = threadIdx.x >> 6;
    const int ks = blockIdx.x & (KSPLIT - 1);
    const int rb = blockIdx.x >> 3;                 // 0..127, 64 rows each
    const int r0 = rb * 64 + wave * 16;
    const int batch = rb >> 5;                      // 32 row-blocks per batch
    const int fm = lane & 15, fq = lane >> 4;
    const int kbase = ks * (D_INN / KSPLIT);        // 512-wide K chunk
    const unsigned short* pa = xb + (size_t)(r0 + fm) * D_INN + kbase + fq * 8;
    const unsigned short* pb = dw + ((size_t)batch * RANKN + fm) * D_INN + kbase + fq * 8;
    floatx4 acc0 = {0.f, 0.f, 0.f, 0.f}, acc1 = {0.f, 0.f, 0.f, 0.f};
    #pragma unroll
    for (int k0 = 0; k0 < D_INN / KSPLIT; k0 += 64) {
        short8 a0 = *(const short8*)(pa + k0);
        short8 b0 = *(const short8*)(pb + k0);
        short8 a1 = *(const short8*)(pa + k0 + 32);
        short8 b1 = *(const short8*)(pb + k0 + 32);
        acc0 = __builtin_amdgcn_mfma_f32_16x16x32_bf16(a0, b0, acc0, 0, 0, 0);
        acc1 = __builtin_amdgcn_mfma_f32_16x16x32_bf16(a1, b1, acc1, 0, 0, 0);
    }
    #pragma unroll
    for (int r = 0; r < 4; ++r) {
        int grow = r0 + fq * 4 + r;                 // C layout: row = quad*4+reg, col = lane&15
        part[((size_t)ks * M_N + grow) * RANKN + fm] = acc0[r] + acc1[r];
    }
}

// ------------- reduce partials -> lr_pad[m][0..15] bf16, [16..31]=0 -------------
__global__ __launch_bounds__(256) void lowrank_reduce_kernel(
    const float* __restrict__ part,        // [KSPLIT][M][16]
    unsigned short* __restrict__ lr)       // [M][32] bf16
{
    int t = blockIdx.x * 256 + threadIdx.x;         // M_N*16 threads
    int m = t >> 4, r = t & 15;
    float s = 0.f;
    #pragma unroll
    for (int p = 0; p < KSPLIT; ++p)
        s += part[((size_t)p * M_N + m) * RANKN + r];
    lr[(size_t)m * 32 + r] = f2b(s);
    lr[(size_t)m * 32 + 16 + r] = 0;
}

// ------------- main GEMM: out = x @ W^T + bias + (lr_pad @ up_pad^T as the 129th K-step) -------------
// m97 structure: 128x128 tile, BK=32, 4 waves (2x2 of 64x64), global_load_lds width 16.
__global__ __launch_bounds__(256, 3) void gemm_kernel(
    const unsigned short* __restrict__ xb,   // [M][K] bf16
    const unsigned short* __restrict__ Wb,   // [N][K] bf16
    const unsigned short* __restrict__ lr,   // [M][32] bf16
    const unsigned short* __restrict__ up,   // [B][N][32] bf16 (x2 scale folded)
    const float* __restrict__ bias,          // [N]
    float* __restrict__ out)                 // [M][N]
{
    __shared__ __align__(16) unsigned short As[128 * 32];  // 8 KB
    __shared__ __align__(16) unsigned short Bs[128 * 32];  // 8 KB

    const int t = threadIdx.x;
    const int lane = t & 63, wave = t >> 6;
    const int m0 = blockIdx.y * 128, n0 = blockIdx.x * 128;
    const int batch = m0 >> 11;                 // 2048 rows / batch

    const int srow = wave * 16 + (lane >> 2);
    const int scol = (lane & 3) * 8;
    const int fm = lane & 15, fq = lane >> 4;
    const int wm = wave >> 1, wn = wave & 1;

    floatx4 acc[4][4];
    #pragma unroll
    for (int i = 0; i < 4; ++i)
        #pragma unroll
        for (int j = 0; j < 4; ++j)
            acc[i][j] = (floatx4){0.f, 0.f, 0.f, 0.f};

    unsigned short* sA0 = As + wave * 512;
    unsigned short* sA1 = As + 2048 + wave * 512;
    unsigned short* sB0 = Bs + wave * 512;
    unsigned short* sB1 = Bs + 2048 + wave * 512;

    const unsigned short* gA0 = xb + (size_t)(m0 + srow) * D_INN + scol;
    const unsigned short* gA1 = gA0 + (size_t)64 * D_INN;
    const unsigned short* gB0 = Wb + (size_t)(n0 + srow) * D_INN + scol;
    const unsigned short* gB1 = gB0 + (size_t)64 * D_INN;

    auto compute_step = [&]() {
        short8 af[4], bf[4];
        #pragma unroll
        for (int mi = 0; mi < 4; ++mi)
            af[mi] = *(const short8*)(As + (wm * 64 + mi * 16 + fm) * 32 + fq * 8);
        #pragma unroll
        for (int ni = 0; ni < 4; ++ni)
            bf[ni] = *(const short8*)(Bs + (wn * 64 + ni * 16 + fm) * 32 + fq * 8);
        #pragma unroll
        for (int mi = 0; mi < 4; ++mi)
            #pragma unroll
            for (int ni = 0; ni < 4; ++ni)
                acc[mi][ni] = __builtin_amdgcn_mfma_f32_16x16x32_bf16(
                    af[mi], bf[ni], acc[mi][ni], 0, 0, 0);
    };

    #pragma unroll 1
    for (int kt = 0; kt < D_INN / 32; ++kt) {
        gld16(gA0, sA0); gld16(gA1, sA1);
        gld16(gB0, sB0); gld16(gB1, sB1);
        gA0 += 32; gA1 += 32; gB0 += 32; gB1 += 32;
        __syncthreads();
        compute_step();
        __syncthreads();
    }

    // 129th K-step: the rank-16 LoRA delta, padded to 32 (cols 16..31 are zero)
    {
        const unsigned short* tA0 = lr + (size_t)(m0 + srow) * 32 + scol;
        const unsigned short* tA1 = tA0 + 64 * 32;
        const unsigned short* tB0 = up + ((size_t)batch * D_OUTN + n0 + srow) * 32 + scol;
        const unsigned short* tB1 = tB0 + 64 * 32;
        gld16(tA0, sA0); gld16(tA1, sA1);
        gld16(tB0, sB0); gld16(tB1, sB1);
        __syncthreads();
        compute_step();
    }

    // epilogue: + bias, store f32. C layout: col = lane&15, row = quad*4 + reg
    #pragma unroll
    for (int ni = 0; ni < 4; ++ni) {
        const int col = n0 + wn * 64 + ni * 16 + fm;
        const float bv = bias[col];
        #pragma unroll
        for (int mi = 0; mi < 4; ++mi) {
            const int row = m0 + wm * 64 + mi * 16 + fq * 4;
            float* op = out + (size_t)row * D_OUTN + col;
            #pragma unroll
            for (int r = 0; r < 4; ++r)
                op[(size_t)r * D_OUTN] = acc[mi][ni][r] + bv;
        }
    }
}

extern "C" void kernel_launch(void* const* d_in, const int* in_sizes, int n_in,
                              void* d_out, int out_size, void* d_ws, size_t ws_size,
                              hipStream_t stream) {
    const float* x          = (const float*)d_in[0];  // [B,S,D_IN]
    const float* W          = (const float*)d_in[1];  // [D_OUT,D_IN]
    const float* bias       = (const float*)d_in[2];  // [D_OUT]
    const float* down_aux   = (const float*)d_in[3];  // [D_IN,64]
    const float* up_aux     = (const float*)d_in[4];  // [64,D_OUT]
    const float* hyper_down = (const float*)d_in[5];  // [B,64,16]
    const float* hyper_up   = (const float*)d_in[6];  // [B,16,64]
    float* out = (float*)d_out;
    (void)in_sizes; (void)n_in; (void)out_size; (void)ws_size;

    // workspace layout (bf16/ushort elements), ~103 MB
    unsigned short* ws = (unsigned short*)d_ws;
    unsigned short* Wb = ws;                                   // [4096][4096]
    unsigned short* xb = Wb + (size_t)D_OUTN * D_INN;          // [8192][4096]
    unsigned short* lr = xb + (size_t)M_N * D_INN;             // [8192][32]
    unsigned short* up = lr + (size_t)M_N * 32;                // [4][4096][32]
    unsigned short* dw = up + (size_t)B_N * D_OUTN * 32;       // [4][16][4096]
    // low-rank partials live in d_out (gemm fully overwrites it afterwards)
    float* part = (float*)d_out;                               // [8][8192][16] = 4 MB

    const int nW8 = D_OUTN * D_INN / 8;                        // 2,097,152
    const int nX8 = M_N * D_INN / 8;                           // 4,194,304
    cast2_bf16_kernel<<<(nW8 + nX8) / 256, 256, 0, stream>>>(W, Wb, nW8, x, xb, nX8);
    build_factors_kernel<<<dim3(D_INN / 256, B_N, 2), 256, 0, stream>>>(
        down_aux, hyper_down, up_aux, hyper_up, dw, up);
    lowrank_split_kernel<<<(M_N / 64) * KSPLIT, 256, 0, stream>>>(xb, dw, part);
    lowrank_reduce_kernel<<<M_N * RANKN / 256, 256, 0, stream>>>(part, lr);
    gemm_kernel<<<dim3(D_OUTN / 128, M_N / 128), 256, 0, stream>>>(xb, Wb, lr, up, bias, out);
}

// Round 3
// 447.533 us; speedup vs baseline: 1.3792x; 1.3383x over previous
//
#include <hip/hip_runtime.h>
#include <hip/hip_bf16.h>

// Problem constants (WrappedLoRALinear)
#define B_N   4
#define S_N   2048
#define D_INN 4096
#define D_OUTN 4096
#define RANKN 16
#define AUX_DN 64
#define AUX_UN 64
#define M_N (B_N * S_N)   // 8192 rows
#define KSPLIT 8          // lowrank K-split factor (K-chunk = 512)

typedef __attribute__((ext_vector_type(8))) short  short8;   // 8 bf16
typedef __attribute__((ext_vector_type(4))) float  floatx4;  // MFMA C/D frag (16x16)
typedef __attribute__((ext_vector_type(4))) int    int4v;    // 16 B
typedef __attribute__((ext_vector_type(8))) int    int8v;    // 32 fp8 = MFMA A/B frag (K=128)

#define SCALE_ONE   ((int)0x7F7F7F7F)  // E8M0 2^0 in all bytes
#define SCALE_2M6   ((int)0x79797979)  // E8M0 2^-6 in all bytes (undo W*64)

// f32 -> bf16 (round-to-nearest-even)
__device__ __forceinline__ unsigned short f2b(float f) {
    unsigned int u = __float_as_uint(f);
    u += 0x7FFFu + ((u >> 16) & 1u);
    return (unsigned short)(u >> 16);
}

// pack 4 f32 -> 4 fp8 e4m3 bytes
__device__ __forceinline__ int pk4(float a, float b, float c, float d) {
    int v = __builtin_amdgcn_cvt_pk_fp8_f32(a, b, 0, false);
    v = __builtin_amdgcn_cvt_pk_fp8_f32(c, d, v, true);
    return v;
}

// async global->LDS, 16B per lane; LDS dest = wave-uniform base + lane*16
__device__ __forceinline__ void gld16(const void* g, void* l) {
    __builtin_amdgcn_global_load_lds(
        (const __attribute__((address_space(1))) unsigned int*)g,
        (__attribute__((address_space(3))) unsigned int*)l,
        16, 0, 0);
}

// ---------------- fused f32 -> fp8 cast: W*64 then x (16 elems / thread) ----------------
__global__ __launch_bounds__(256) void cast_fp8_kernel(
    const float* __restrict__ srcA, unsigned char* __restrict__ dstA, int nA, float scA,
    const float* __restrict__ srcB, unsigned char* __restrict__ dstB, int nB, float scB) {
    int i = blockIdx.x * 256 + threadIdx.x;
    const float* src; unsigned char* dst; int j; float sc;
    if (i < nA) { src = srcA; dst = dstA; j = i; sc = scA; }
    else        { j = i - nA; if (j >= nB) return; src = srcB; dst = dstB; sc = scB; }
    const floatx4* s4 = (const floatx4*)src + (size_t)j * 4;
    int4v o;
    #pragma unroll
    for (int u = 0; u < 4; ++u) {
        floatx4 v = s4[u];
        o[u] = pk4(v[0] * sc, v[1] * sc, v[2] * sc, v[3] * sc);
    }
    ((int4v*)dst)[j] = o;
}

// ------------- fused factor build: z=0 -> down_bf16, z=1 -> up_pad -------------
__global__ __launch_bounds__(256) void build_factors_kernel(
    const float* __restrict__ down_aux,   // [D_IN][64]
    const float* __restrict__ hyper_down, // [B][64][16]
    const float* __restrict__ up_aux,     // [64][D_OUT]
    const float* __restrict__ hyper_up,   // [B][16][64]
    unsigned short* __restrict__ down_b,  // [B][16][D_IN] bf16
    unsigned short* __restrict__ up_pad)  // [B][D_OUT][32] bf16
{
    __shared__ float h[AUX_DN * RANKN];  // 4 KB
    const int b = blockIdx.y;
    const int i = blockIdx.x * 256 + threadIdx.x;
    if (blockIdx.z == 0) {
        for (int t = threadIdx.x; t < AUX_DN * RANKN; t += 256)
            h[t] = hyper_down[(size_t)b * AUX_DN * RANKN + t];
        __syncthreads();
        float acc[RANKN];
        #pragma unroll
        for (int r = 0; r < RANKN; ++r) acc[r] = 0.f;
        const floatx4* da4 = (const floatx4*)(down_aux + (size_t)i * AUX_DN);
        #pragma unroll
        for (int a4 = 0; a4 < AUX_DN / 4; ++a4) {
            floatx4 v = da4[a4];
            #pragma unroll
            for (int jj = 0; jj < 4; ++jj) {
                float vv = v[jj];
                #pragma unroll
                for (int r = 0; r < RANKN; ++r) acc[r] += vv * h[(a4 * 4 + jj) * RANKN + r];
            }
        }
        #pragma unroll
        for (int r = 0; r < RANKN; ++r)
            down_b[((size_t)b * RANKN + r) * D_INN + i] = f2b(acc[r]);
    } else {
        for (int t = threadIdx.x; t < RANKN * AUX_UN; t += 256)
            h[t] = hyper_up[(size_t)b * RANKN * AUX_UN + t];
        __syncthreads();
        float acc[RANKN];
        #pragma unroll
        for (int r = 0; r < RANKN; ++r) acc[r] = 0.f;
        for (int a = 0; a < AUX_UN; ++a) {
            float v = up_aux[(size_t)a * D_OUTN + i];
            #pragma unroll
            for (int r = 0; r < RANKN; ++r) acc[r] += v * h[r * AUX_UN + a];
        }
        short8 o0, o1, z;
        #pragma unroll
        for (int r = 0; r < 8; ++r) {
            o0[r] = (short)f2b(2.f * acc[r]);
            o1[r] = (short)f2b(2.f * acc[8 + r]);
            z[r] = 0;
        }
        short8* dst = (short8*)(up_pad + ((size_t)b * D_OUTN + i) * 32);
        dst[0] = o0; dst[1] = o1; dst[2] = z; dst[3] = z;
    }
}

// ------------- low_rank partials from f32 x (in-reg bf16 cvt), K-split -------------
__device__ __forceinline__ short8 cvt8(const float* p) {
    const floatx4* p4 = (const floatx4*)p;
    floatx4 a = p4[0], b = p4[1];
    short8 o;
    o[0] = (short)f2b(a[0]); o[1] = (short)f2b(a[1]);
    o[2] = (short)f2b(a[2]); o[3] = (short)f2b(a[3]);
    o[4] = (short)f2b(b[0]); o[5] = (short)f2b(b[1]);
    o[6] = (short)f2b(b[2]); o[7] = (short)f2b(b[3]);
    return o;
}

__global__ __launch_bounds__(256) void lowrank_split_kernel(
    const float* __restrict__ x,            // [M][D_IN] f32
    const unsigned short* __restrict__ dw,  // [B][16][D_IN] bf16
    float* __restrict__ part)               // [KSPLIT][M][16] f32
{
    const int lane = threadIdx.x & 63, wave = threadIdx.x >> 6;
    const int ks = blockIdx.x & (KSPLIT - 1);
    const int rb = blockIdx.x >> 3;                 // 0..127, 64 rows each
    const int r0 = rb * 64 + wave * 16;
    const int batch = rb >> 5;
    const int fm = lane & 15, fq = lane >> 4;
    const int kbase = ks * (D_INN / KSPLIT);        // 512-wide K chunk
    const float* pa = x + (size_t)(r0 + fm) * D_INN + kbase + fq * 8;
    const unsigned short* pb = dw + ((size_t)batch * RANKN + fm) * D_INN + kbase + fq * 8;
    floatx4 acc0 = {0.f, 0.f, 0.f, 0.f}, acc1 = {0.f, 0.f, 0.f, 0.f};
    #pragma unroll
    for (int k0 = 0; k0 < D_INN / KSPLIT; k0 += 64) {
        short8 a0 = cvt8(pa + k0);
        short8 b0 = *(const short8*)(pb + k0);
        short8 a1 = cvt8(pa + k0 + 32);
        short8 b1 = *(const short8*)(pb + k0 + 32);
        acc0 = __builtin_amdgcn_mfma_f32_16x16x32_bf16(a0, b0, acc0, 0, 0, 0);
        acc1 = __builtin_amdgcn_mfma_f32_16x16x32_bf16(a1, b1, acc1, 0, 0, 0);
    }
    #pragma unroll
    for (int r = 0; r < 4; ++r) {
        int grow = r0 + fq * 4 + r;                 // C layout: row = quad*4+reg, col = lane&15
        part[((size_t)ks * M_N + grow) * RANKN + fm] = acc0[r] + acc1[r];
    }
}

// ------------- reduce partials -> lr_pad[m][0..15] bf16, [16..31]=0 -------------
__global__ __launch_bounds__(256) void lowrank_reduce_kernel(
    const float* __restrict__ part, unsigned short* __restrict__ lr)
{
    int t = blockIdx.x * 256 + threadIdx.x;
    int m = t >> 4, r = t & 15;
    float s = 0.f;
    #pragma unroll
    for (int p = 0; p < KSPLIT; ++p)
        s += part[((size_t)p * M_N + m) * RANKN + r];
    lr[(size_t)m * 32 + r] = f2b(s);
    lr[(size_t)m * 32 + 16 + r] = 0;
}

// ------------- main GEMM: MX-fp8 K=128 main loop + bf16 LoRA K-step + bias -------------
// 128x128 tile, BK=128 fp8 (16 KB + 16 KB LDS), 4 waves (2x2 of 64x64).
// LDS rows are 128 B (=32 banks): XOR-swizzle 16B halves (pos p holds global half p^(row&7))
// applied at the *global* address of global_load_lds -> 2-way (free) frag reads.
__global__ __launch_bounds__(256, 3) void gemm_kernel(
    const unsigned char* __restrict__ xq,   // [M][4096] fp8 e4m3
    const unsigned char* __restrict__ Wq,   // [N][4096] fp8 e4m3 (x64 pre-scale)
    const unsigned short* __restrict__ lr,  // [M][32] bf16
    const unsigned short* __restrict__ up,  // [B][N][32] bf16 (x2 scale folded)
    const float* __restrict__ bias,         // [N]
    float* __restrict__ out)                // [M][N]
{
    __shared__ __align__(16) unsigned char As[128 * 128];  // 16 KB
    __shared__ __align__(16) unsigned char Bs[128 * 128];  // 16 KB

    const int t = threadIdx.x;
    const int lane = t & 63, wave = t >> 6;
    const int m0 = blockIdx.y * 128, n0 = blockIdx.x * 128;
    const int batch = m0 >> 11;                 // 2048 rows / batch
    const int fm = lane & 15, fq = lane >> 4;
    const int wm = wave >> 1, wn = wave & 1;

    floatx4 acc[4][4];
    #pragma unroll
    for (int i = 0; i < 4; ++i)
        #pragma unroll
        for (int j = 0; j < 4; ++j)
            acc[i][j] = (floatx4){0.f, 0.f, 0.f, 0.f};

    // staging: each wave-issue = 1024 B = 8 rows x 128 B; lane -> (row lane>>3, half lane&7)
    const int lrow = wave * 8 + (lane >> 3);                   // + i*32 per issue
    const int sbyte = (((lane & 7) ^ (lane >> 3)) << 4);       // swizzled global 16B-half
    const unsigned char* gA = xq + (size_t)(m0 + lrow) * D_INN + sbyte;
    const unsigned char* gB = Wq + (size_t)(n0 + lrow) * D_INN + sbyte;
    unsigned char* sA = As + wave * 1024;
    unsigned char* sB = Bs + wave * 1024;

    // frag reads: lane (fm,fq) wants 16B halves 2fq, 2fq+1 of row; stored at (h ^ (row&7))
    const int swz = fm & 7;
    const unsigned char* arow = As + (wm * 64 + fm) * 128;
    const unsigned char* brow = Bs + (wn * 64 + fm) * 128;
    const int lo_off = ((2 * fq) ^ swz) << 4;
    const int hi_off = ((2 * fq + 1) ^ swz) << 4;

    #pragma unroll 1
    for (int kt = 0; kt < D_INN / 128; ++kt) {
        const size_t kb = (size_t)kt * 128;
        #pragma unroll
        for (int i = 0; i < 4; ++i) {
            gld16(gA + (size_t)i * 32 * D_INN + kb, sA + i * 4096);
            gld16(gB + (size_t)i * 32 * D_INN + kb, sB + i * 4096);
        }
        __syncthreads();
        int8v af[4], bf[4];
        #pragma unroll
        for (int mi = 0; mi < 4; ++mi) {
            int4v lo = *(const int4v*)(arow + mi * 2048 + lo_off);
            int4v hi = *(const int4v*)(arow + mi * 2048 + hi_off);
            af[mi][0] = lo[0]; af[mi][1] = lo[1]; af[mi][2] = lo[2]; af[mi][3] = lo[3];
            af[mi][4] = hi[0]; af[mi][5] = hi[1]; af[mi][6] = hi[2]; af[mi][7] = hi[3];
        }
        #pragma unroll
        for (int ni = 0; ni < 4; ++ni) {
            int4v lo = *(const int4v*)(brow + ni * 2048 + lo_off);
            int4v hi = *(const int4v*)(brow + ni * 2048 + hi_off);
            bf[ni][0] = lo[0]; bf[ni][1] = lo[1]; bf[ni][2] = lo[2]; bf[ni][3] = lo[3];
            bf[ni][4] = hi[0]; bf[ni][5] = hi[1]; bf[ni][6] = hi[2]; bf[ni][7] = hi[3];
        }
        #pragma unroll
        for (int mi = 0; mi < 4; ++mi)
            #pragma unroll
            for (int ni = 0; ni < 4; ++ni)
                acc[mi][ni] = __builtin_amdgcn_mfma_scale_f32_16x16x128_f8f6f4(
                    af[mi], bf[ni], acc[mi][ni],
                    0, 0,                 // cbsz=fp8(e4m3) A, blgp=fp8(e4m3) B
                    0, SCALE_ONE,         // A scale = 1.0 (uniform -> layout-proof)
                    0, SCALE_2M6);        // B scale = 2^-6 (undo W*64)
        __syncthreads();
    }

    // LoRA K-step in bf16 (same 16x16 C/D layout): LDS reused as [128][32] bf16 tiles
    {
        unsigned short* As16 = (unsigned short*)As;
        unsigned short* Bs16 = (unsigned short*)Bs;
        const int srow = wave * 16 + (lane >> 2);
        const int scol = (lane & 3) * 8;
        const unsigned short* tA0 = lr + (size_t)(m0 + srow) * 32 + scol;
        const unsigned short* tB0 = up + ((size_t)batch * D_OUTN + n0 + srow) * 32 + scol;
        gld16(tA0, As + wave * 1024);
        gld16(tA0 + 64 * 32, As + 4096 + wave * 1024);
        gld16(tB0, Bs + wave * 1024);
        gld16(tB0 + 64 * 32, Bs + 4096 + wave * 1024);
        __syncthreads();
        short8 a2[4], b2[4];
        #pragma unroll
        for (int mi = 0; mi < 4; ++mi)
            a2[mi] = *(const short8*)(As16 + (wm * 64 + mi * 16 + fm) * 32 + fq * 8);
        #pragma unroll
        for (int ni = 0; ni < 4; ++ni)
            b2[ni] = *(const short8*)(Bs16 + (wn * 64 + ni * 16 + fm) * 32 + fq * 8);
        #pragma unroll
        for (int mi = 0; mi < 4; ++mi)
            #pragma unroll
            for (int ni = 0; ni < 4; ++ni)
                acc[mi][ni] = __builtin_amdgcn_mfma_f32_16x16x32_bf16(
                    a2[mi], b2[ni], acc[mi][ni], 0, 0, 0);
    }

    // epilogue: + bias, store f32. C layout: col = lane&15, row = quad*4 + reg
    #pragma unroll
    for (int ni = 0; ni < 4; ++ni) {
        const int col = n0 + wn * 64 + ni * 16 + fm;
        const float bv = bias[col];
        #pragma unroll
        for (int mi = 0; mi < 4; ++mi) {
            const int row = m0 + wm * 64 + mi * 16 + fq * 4;
            float* op = out + (size_t)row * D_OUTN + col;
            #pragma unroll
            for (int r = 0; r < 4; ++r)
                op[(size_t)r * D_OUTN] = acc[mi][ni][r] + bv;
        }
    }
}

extern "C" void kernel_launch(void* const* d_in, const int* in_sizes, int n_in,
                              void* d_out, int out_size, void* d_ws, size_t ws_size,
                              hipStream_t stream) {
    const float* x          = (const float*)d_in[0];  // [B,S,D_IN]
    const float* W          = (const float*)d_in[1];  // [D_OUT,D_IN]
    const float* bias       = (const float*)d_in[2];  // [D_OUT]
    const float* down_aux   = (const float*)d_in[3];  // [D_IN,64]
    const float* up_aux     = (const float*)d_in[4];  // [64,D_OUT]
    const float* hyper_down = (const float*)d_in[5];  // [B,64,16]
    const float* hyper_up   = (const float*)d_in[6];  // [B,16,64]
    float* out = (float*)d_out;
    (void)in_sizes; (void)n_in; (void)out_size; (void)ws_size;

    // workspace layout: fp8 W (16 MB) + fp8 x (32 MB) + small bf16 factors
    unsigned char* ws8 = (unsigned char*)d_ws;
    unsigned char* Wq = ws8;                                        // [4096][4096] fp8
    unsigned char* xq = Wq + (size_t)D_OUTN * D_INN;                // [8192][4096] fp8
    unsigned short* lr = (unsigned short*)(xq + (size_t)M_N * D_INN); // [8192][32] bf16
    unsigned short* up = lr + (size_t)M_N * 32;                     // [4][4096][32] bf16
    unsigned short* dw = up + (size_t)B_N * D_OUTN * 32;            // [4][16][4096] bf16
    float* part = (float*)d_out;  // [8][8192][16] f32 scratch; gemm overwrites d_out fully

    const int nW16 = D_OUTN * D_INN / 16;     // 1,048,576
    const int nX16 = M_N * D_INN / 16;        // 2,097,152
    cast_fp8_kernel<<<(nW16 + nX16) / 256, 256, 0, stream>>>(
        W, Wq, nW16, 64.f, x, xq, nX16, 1.f);
    build_factors_kernel<<<dim3(D_INN / 256, B_N, 2), 256, 0, stream>>>(
        down_aux, hyper_down, up_aux, hyper_up, dw, up);
    lowrank_split_kernel<<<(M_N / 64) * KSPLIT, 256, 0, stream>>>(x, dw, part);
    lowrank_reduce_kernel<<<M_N * RANKN / 256, 256, 0, stream>>>(part, lr);
    gemm_kernel<<<dim3(D_OUTN / 128, M_N / 128), 256, 0, stream>>>(xq, Wq, lr, up, bias, out);
}